// Round 3
// baseline (283.986 us; speedup 1.0000x reference)
//
#include <hip/hip_runtime.h>
#include <hip/hip_bf16.h>

// Problem constants
#define NN 384
#define CUTOFF2 144.0f
#define GAMMA 1.7777778f   // (16/12)^2

// packed B-frag layout per layer (u32 units): [W1b 8192 | We 2048 | W2 8192 | C1 8192]
#define PK_L 26624
#define PK_WE 8192
#define PK_W2 10240
#define PK_C1 18432

#define G_EDGE 256
#define STG_F32 1152                    // 32 rows x 36 f32 per-wave stage
#define EDGE_SMEM ((PK_L + 8*STG_F32)*4)  // 143360 B

// ws byte offsets
#define O_XA 0
#define O_XB 4608
#define O_H 9216
#define O_A 205824
#define O_AGG 402432
#define O_HBF 599040
#define O_ELIST 697344
#define O_CNT 992256
#define O_UCNT 993792
#define O_UNITS 993856
#define O_DONE 1012288
#define O_PK 1034816

typedef __bf16 bf16x8 __attribute__((ext_vector_type(8)));
typedef float f32x4 __attribute__((ext_vector_type(4)));

__device__ __forceinline__ unsigned short f2bf(float f){
  unsigned u = __float_as_uint(f);
  return (unsigned short)((u + 0x7fffu + ((u >> 16) & 1u)) >> 16);  // RNE
}
__device__ __forceinline__ unsigned pk2(float a, float b){
  return ((unsigned)f2bf(b) << 16) | f2bf(a);
}
__device__ __forceinline__ float silu(float x){ return x / (1.0f + __expf(-x)); }

// ---- pack weights into MFMA B-fragment order (bf16 pairs), 3 layers; block 312 = center+init
__global__ void k_prep(const float* __restrict__ eW1, const float* __restrict__ eW2,
                       const float* __restrict__ cW1, unsigned* __restrict__ pk,
                       const float* __restrict__ anchor, float* __restrict__ xA,
                       float* __restrict__ xB, int* __restrict__ done){
  if (blockIdx.x == 312) {
    __shared__ float ssum[3];
    int t = threadIdx.x;
    if (t < 3) { ssum[t] = 0.f; done[t] = 0; }
    __syncthreads();
    for (int n = t; n < 384; n += 256) {
      atomicAdd(&ssum[0], anchor[n*3]);
      atomicAdd(&ssum[1], anchor[n*3+1]);
      atomicAdd(&ssum[2], anchor[n*3+2]);
    }
    __syncthreads();
    float m0 = ssum[0]*(1.f/384.f), m1 = ssum[1]*(1.f/384.f), m2 = ssum[2]*(1.f/384.f);
    for (int n = t; n < 384; n += 256) {
      float v0 = anchor[n*3]-m0, v1 = anchor[n*3+1]-m1, v2 = anchor[n*3+2]-m2;
      xA[n*3]=v0; xA[n*3+1]=v1; xA[n*3+2]=v2;
      xB[n*3]=v0; xB[n*3+1]=v1; xB[n*3+2]=v2;
    }
    return;
  }
  int t = blockIdx.x * 256 + threadIdx.x;
  int layer = t / PK_L, r = t % PK_L;
  const float* src; int fr; int isWe = 0;
  if (r < PK_WE)        { fr = r;          src = eW1 + (layer*272 + 128)*128; }
  else if (r < PK_W2)   { fr = r - PK_WE;  src = eW1 + (layer*272 + 256)*128; isWe = 1; }
  else if (r < PK_C1)   { fr = r - PK_W2;  src = eW2 + layer*128*128; }
  else                  { fr = r - PK_C1;  src = cW1 + layer*128*128; }
  int tp = fr & 3, l = (fr >> 2) & 63, nc = fr >> 8;
  int n, k;
  if (!isWe) { n = nc >> 2; int c = nc & 3; k = c*32 + ((l>>4)<<3) + 2*tp; }
  else       { n = nc;                      k = ((l>>4)<<3) + 2*tp; }
  int nn = n*16 + (l & 15);
  float w0, w1;
  if (isWe) { w0 = (k < 16)   ? src[k*128+nn]     : 0.f;
              w1 = (k+1 < 16) ? src[(k+1)*128+nn] : 0.f; }
  else      { w0 = src[k*128+nn]; w1 = src[(k+1)*128+nn]; }
  pk[t] = ((unsigned)f2bf(w1) << 16) | f2bf(w0);
}

// ---- shared scan/units tail (scan x, pad elist to x32, last block builds unit table)
__device__ __forceinline__ void scan_units_tail(
    int i, int o, const float* __restrict__ x, unsigned short* __restrict__ elist,
    int* __restrict__ counts, int* __restrict__ units, int* __restrict__ Ucnt,
    int* __restrict__ doneSlot, int* scnt, int* sticket){
  float xi0 = x[i*3], xi1 = x[i*3+1], xi2 = x[i*3+2];
  for (int j = o; j < 384; j += 128) {
    float d0 = xi0-x[j*3], d1 = xi1-x[j*3+1], d2 = xi2-x[j*3+2];
    float dd = d0*d0 + d1*d1 + d2*d2;
    bool msk = ((dd < CUTOFF2) && (j != i)) || (j == i-1) || (j == i+1);
    if (msk) { int ss = atomicAdd(scnt, 1); elist[i*384 + ss] = (unsigned short)j; }
  }
  __syncthreads();
  int cnt = *scnt;
  if (o < ((32 - (cnt & 31)) & 31)) elist[i*384 + cnt + o] = (unsigned short)i;
  if (o == 0) counts[i] = cnt;
  __threadfence();
  if (o == 0) *sticket = atomicAdd(doneSlot, 1);
  __syncthreads();
  if (*sticket == 383 && o < 64) {
    __threadfence();
    int uu[6]; int tot = 0;
    #pragma unroll
    for (int k2 = 0; k2 < 6; ++k2) { uu[k2] = (counts[o*6+k2] + 31) >> 5; tot += uu[k2]; }
    int sc = tot;
    #pragma unroll
    for (int off = 1; off < 64; off <<= 1) { int nb = __shfl_up(sc, off); if (o >= off) sc += nb; }
    int base = sc - tot;
    #pragma unroll
    for (int k2 = 0; k2 < 6; ++k2) {
      for (int bb = 0; bb < uu[k2]; ++bb) units[base+bb] = (o*6+k2) | (bb << 16);
      base += uu[k2];
    }
    if (o == 63) Ucnt[0] = sc;
  }
}

// ---- h = z@projW + b; hbf; A = h@W1a + eb1; zero agg; + fused scan/units (layer 0)
__global__ void k_projAB(const float* __restrict__ z, const float* __restrict__ pW,
                         const float* __restrict__ pb, const float* __restrict__ eW1,
                         const float* __restrict__ eb1, float* __restrict__ h,
                         unsigned short* __restrict__ hbf, float* __restrict__ A,
                         float* __restrict__ agg, const float* __restrict__ x,
                         unsigned short* __restrict__ elist, int* __restrict__ counts,
                         int* __restrict__ units, int* __restrict__ Ucnt,
                         int* __restrict__ doneSlot){
  __shared__ float sz[64]; __shared__ float sh[128];
  __shared__ int scnt; __shared__ int sticket;
  int i = blockIdx.x, o = threadIdx.x;
  if (o == 0) scnt = 0;
  if (o < 64) sz[o] = z[i*64 + o];
  __syncthreads();
  float hh = pb[o];
  #pragma unroll 8
  for (int k = 0; k < 64; ++k) hh += sz[k] * pW[k*128 + o];
  h[i*128 + o] = hh; hbf[i*128 + o] = f2bf(hh); sh[o] = hh; agg[i*128 + o] = 0.f;
  __syncthreads();
  float aa = eb1[o];
  for (int k = 0; k < 128; ++k) aa += sh[k] * eW1[k*128 + o];
  A[i*128 + o] = aa;
  scan_units_tail(i, o, x, elist, counts, units, Ucnt, doneSlot, &scnt, &sticket);
}

// ---- node update, A/hbf for next layer, zero agg, seed xdst, + fused scan/units
__global__ void k_nodeAB(const float* __restrict__ nW1, const float* __restrict__ nb1,
                         const float* __restrict__ nW2, const float* __restrict__ nb2,
                         const float* __restrict__ eW1n, const float* __restrict__ eb1n,
                         float* __restrict__ h, unsigned short* __restrict__ hbf,
                         float* __restrict__ agg, float* __restrict__ A,
                         const float* __restrict__ xsrc, float* __restrict__ xdst,
                         unsigned short* __restrict__ elist, int* __restrict__ counts,
                         int* __restrict__ units, int* __restrict__ Ucnt,
                         int* __restrict__ doneSlot){
  __shared__ float sh[128], sg[128], st[128], shn[128];
  __shared__ int scnt; __shared__ int sticket;
  int i = blockIdx.x, o = threadIdx.x;
  if (o == 0) scnt = 0;
  sh[o] = h[i*128 + o]; sg[o] = agg[i*128 + o]; agg[i*128 + o] = 0.f;
  if (o < 3) xdst[i*3 + o] = xsrc[i*3 + o];
  __syncthreads();
  float a = nb1[o];
  for (int k = 0; k < 128; ++k) a += sh[k] * nW1[k*128 + o];
  for (int k = 0; k < 128; ++k) a += sg[k] * nW1[(128 + k)*128 + o];
  st[o] = silu(a);
  __syncthreads();
  float hn = sh[o] + nb2[o];
  for (int k = 0; k < 128; ++k) hn += st[k] * nW2[k*128 + o];
  h[i*128 + o] = hn; hbf[i*128 + o] = f2bf(hn); shn[o] = hn;
  __syncthreads();
  float aa = eb1n[o];
  for (int k = 0; k < 128; ++k) aa += shn[k] * eW1n[k*128 + o];
  A[i*128 + o] = aa;
  scan_units_tail(i, o, xsrc, elist, counts, units, Ucnt, doneSlot, &scnt, &sticket);
}

// ---- conflict-free C-layout -> A-frag transpose through per-wave f32 LDS pad
#define TRANSFORM(VA, VB, FA, FB)                                              \
  _Pragma("unroll")                                                            \
  for (int c = 0; c < 4; ++c) {                                                \
    _Pragma("unroll")                                                          \
    for (int tl = 0; tl < 2; ++tl) {                                           \
      int t = 2*c + tl;                                                        \
      _Pragma("unroll")                                                        \
      for (int r = 0; r < 4; ++r) {                                            \
        stg[(quad*4 + r)*36 + tl*16 + col0] = VA[t][r];                        \
        stg[(16 + quad*4 + r)*36 + tl*16 + col0] = VB[t][r];                   \
      }                                                                        \
    }                                                                          \
    __threadfence_block();                                                     \
    float4 lo = *(const float4*)(stg + col0*36 + quad*8);                      \
    float4 hi = *(const float4*)(stg + col0*36 + quad*8 + 4);                  \
    FA[c].u = make_uint4(pk2(lo.x,lo.y), pk2(lo.z,lo.w),                       \
                         pk2(hi.x,hi.y), pk2(hi.z,hi.w));                      \
    float4 lo2 = *(const float4*)(stg + (16 + col0)*36 + quad*8);              \
    float4 hi2 = *(const float4*)(stg + (16 + col0)*36 + quad*8 + 4);          \
    FB[c].u = make_uint4(pk2(lo2.x,lo2.y), pk2(lo2.z,lo2.w),                   \
                         pk2(hi2.x,hi2.y), pk2(hi2.z,hi2.w));                  \
    __threadfence_block();                                                     \
  }

// ---- MFMA edge kernel: wave = one unit (32 same-receiver edges, 2 A-frag sets)
__global__ __launch_bounds__(512, 1) void k_edge(
    const float* __restrict__ x_in, float* __restrict__ x_out,
    const float* __restrict__ Ag, const unsigned short* __restrict__ hbf,
    const unsigned short* __restrict__ elist, const int* __restrict__ counts,
    const int* __restrict__ units, const int* __restrict__ Ucnt,
    float* __restrict__ agg, const unsigned* __restrict__ pkl,
    const float* __restrict__ eb2g, const float* __restrict__ cb1g,
    const float* __restrict__ cw2g){
  extern __shared__ unsigned smem[];
  const int tid = threadIdx.x, q = tid & 63, s = tid >> 6;
  for (int idx = tid; idx < PK_L/4; idx += 512)
    ((uint4*)smem)[idx] = ((const uint4*)pkl)[idx];
  __syncthreads();

  const int col0 = q & 15, quad = q >> 4;
  float eb2v[8], cb1v[8], cw2v[8];
  #pragma unroll
  for (int t = 0; t < 8; ++t) {
    int c = t*16 + col0;
    eb2v[t] = eb2g[c]; cb1v[t] = cb1g[c]; cw2v[t] = cw2g[c];
  }
  float* stg = (float*)(smem + PK_L) + s*STG_F32;
  const int U = Ucnt[0];
  const f32x4 z4 = {0.f, 0.f, 0.f, 0.f};
  union U8 { uint4 u; bf16x8 v; };

  for (int u = blockIdx.x*8 + s; u < U; u += G_EDGE*8) {
    const int desc = units[u];
    const int i = desc & 0xffff, b = desc >> 16;
    int nvalid = counts[i] - b*32; if (nvalid > 32) nvalid = 32;
    const int j0 = (int)elist[i*384 + b*32 + col0];
    const int j1 = (int)elist[i*384 + b*32 + 16 + col0];

    const float xi0 = x_in[i*3], xi1 = x_in[i*3+1], xi2 = x_in[i*3+2];
    const float d0x = xi0 - x_in[j0*3], d0y = xi1 - x_in[j0*3+1], d0z = xi2 - x_in[j0*3+2];
    const float d1x = xi0 - x_in[j1*3], d1y = xi1 - x_in[j1*3+1], d1z = xi2 - x_in[j1*3+2];
    const float dd0 = sqrtf(d0x*d0x + d0y*d0y + d0z*d0z);
    const float dd1 = sqrtf(d1x*d1x + d1y*d1y + d1z*d1z);

    // RBF A-frags (K padded 16->32 with zeros; matching We frags are zero)
    U8 cve0, cve1;
    if (q < 32) {
      #pragma unroll
      for (int tp = 0; tp < 4; ++tp) {
        float k0 = (float)(quad*8 + 2*tp);
        float t00 = dd0 - 0.8f*k0, t01 = dd0 - 0.8f*(k0+1.f);
        float t10 = dd1 - 0.8f*k0, t11 = dd1 - 0.8f*(k0+1.f);
        (&cve0.u.x)[tp] = pk2(__expf(-GAMMA*t00*t00), __expf(-GAMMA*t01*t01));
        (&cve1.u.x)[tp] = pk2(__expf(-GAMMA*t10*t10), __expf(-GAMMA*t11*t11));
      }
    } else { cve0.u = make_uint4(0,0,0,0); cve1.u = make_uint4(0,0,0,0); }

    U8 ha0[4], ha1[4];
    #pragma unroll
    for (int c = 0; c < 4; ++c) {
      ha0[c].u = *(const uint4*)(hbf + j0*128 + c*32 + quad*8);
      ha1[c].u = *(const uint4*)(hbf + j1*128 + c*32 + quad*8);
    }
    float Aval[8];
    #pragma unroll
    for (int t = 0; t < 8; ++t) Aval[t] = Ag[i*128 + t*16 + col0];

    // GEMM1: m1 = silu(h_j@W1b + e@We + A_i), 32 rows
    f32x4 acc0[8], acc1[8];
    #pragma unroll
    for (int t = 0; t < 8; ++t) { acc0[t] = z4; acc1[t] = z4; }
    #pragma unroll
    for (int t = 0; t < 8; ++t) {
      #pragma unroll
      for (int c = 0; c < 4; ++c) {
        bf16x8 w = *(const bf16x8*)(smem + ((t*4 + c)*64 + q)*4);
        acc0[t] = __builtin_amdgcn_mfma_f32_16x16x32_bf16(ha0[c].v, w, acc0[t], 0, 0, 0);
        acc1[t] = __builtin_amdgcn_mfma_f32_16x16x32_bf16(ha1[c].v, w, acc1[t], 0, 0, 0);
      }
      bf16x8 we = *(const bf16x8*)(smem + PK_WE + (t*64 + q)*4);
      acc0[t] = __builtin_amdgcn_mfma_f32_16x16x32_bf16(cve0.v, we, acc0[t], 0, 0, 0);
      acc1[t] = __builtin_amdgcn_mfma_f32_16x16x32_bf16(cve1.v, we, acc1[t], 0, 0, 0);
    }
    #pragma unroll
    for (int t = 0; t < 8; ++t)
      #pragma unroll
      for (int r = 0; r < 4; ++r) {
        acc0[t][r] = silu(acc0[t][r] + Aval[t]);
        acc1[t][r] = silu(acc1[t][r] + Aval[t]);
      }

    U8 a20[4], a21[4];
    TRANSFORM(acc0, acc1, a20, a21);

    // GEMM2: m = silu(m1@eW2 + eb2)
    f32x4 m0[8], m1v[8];
    #pragma unroll
    for (int t = 0; t < 8; ++t) { m0[t] = z4; m1v[t] = z4; }
    #pragma unroll
    for (int t = 0; t < 8; ++t)
      #pragma unroll
      for (int c = 0; c < 4; ++c) {
        bf16x8 w = *(const bf16x8*)(smem + PK_W2 + ((t*4 + c)*64 + q)*4);
        m0[t] = __builtin_amdgcn_mfma_f32_16x16x32_bf16(a20[c].v, w, m0[t], 0, 0, 0);
        m1v[t] = __builtin_amdgcn_mfma_f32_16x16x32_bf16(a21[c].v, w, m1v[t], 0, 0, 0);
      }
    #pragma unroll
    for (int t = 0; t < 8; ++t) {
      float cs = 0.f;
      #pragma unroll
      for (int r = 0; r < 4; ++r) {
        m0[t][r] = silu(m0[t][r] + eb2v[t]);
        m1v[t][r] = silu(m1v[t][r] + eb2v[t]);
        if (quad*4 + r < nvalid) cs += m0[t][r];
        if (16 + quad*4 + r < nvalid) cs += m1v[t][r];
      }
      cs += __shfl_xor(cs, 16); cs += __shfl_xor(cs, 32);
      if (q < 16) atomicAdd(&agg[i*128 + t*16 + q], cs);
    }

    U8 a30[4], a31[4];
    TRANSFORM(m0, m1v, a30, a31);

    // GEMM3: c1 = silu(m@cW1 + cb1); w_row = c1 . cW2
    f32x4 c30[8], c31[8];
    #pragma unroll
    for (int t = 0; t < 8; ++t) { c30[t] = z4; c31[t] = z4; }
    #pragma unroll
    for (int t = 0; t < 8; ++t)
      #pragma unroll
      for (int c = 0; c < 4; ++c) {
        bf16x8 w = *(const bf16x8*)(smem + PK_C1 + ((t*4 + c)*64 + q)*4);
        c30[t] = __builtin_amdgcn_mfma_f32_16x16x32_bf16(a30[c].v, w, c30[t], 0, 0, 0);
        c31[t] = __builtin_amdgcn_mfma_f32_16x16x32_bf16(a31[c].v, w, c31[t], 0, 0, 0);
      }
    float p0[4], p1[4];
    #pragma unroll
    for (int r = 0; r < 4; ++r) {
      float pa = 0.f, pb = 0.f;
      #pragma unroll
      for (int t = 0; t < 8; ++t) {
        pa += silu(c30[t][r] + cb1v[t]) * cw2v[t];
        pb += silu(c31[t][r] + cb1v[t]) * cw2v[t];
      }
      if (quad*4 + r >= nvalid) pa = 0.f;
      if (16 + quad*4 + r >= nvalid) pb = 0.f;
      p0[r] = pa; p1[r] = pb;
    }
    #pragma unroll
    for (int r = 0; r < 4; ++r)
      #pragma unroll
      for (int off = 1; off < 16; off <<= 1) {
        p0[r] += __shfl_xor(p0[r], off);
        p1[r] += __shfl_xor(p1[r], off);
      }
    // dx_i contribution
    float dx0 = 0.f, dx1 = 0.f, dx2 = 0.f;
    #pragma unroll
    for (int r = 0; r < 4; ++r) {
      int el = quad*4 + r;
      float s0 = __shfl(d0x, el), s1 = __shfl(d0y, el), s2 = __shfl(d0z, el);
      if (col0 == 0) { dx0 += p0[r]*s0; dx1 += p0[r]*s1; dx2 += p0[r]*s2; }
      float u0 = __shfl(d1x, el), u1 = __shfl(d1y, el), u2 = __shfl(d1z, el);
      if (col0 == 0) { dx0 += p1[r]*u0; dx1 += p1[r]*u1; dx2 += p1[r]*u2; }
    }
    dx0 += __shfl_xor(dx0, 16); dx0 += __shfl_xor(dx0, 32);
    dx1 += __shfl_xor(dx1, 16); dx1 += __shfl_xor(dx1, 32);
    dx2 += __shfl_xor(dx2, 16); dx2 += __shfl_xor(dx2, 32);
    if (q == 0) {
      atomicAdd(&x_out[i*3 + 0], dx0);
      atomicAdd(&x_out[i*3 + 1], dx1);
      atomicAdd(&x_out[i*3 + 2], dx2);
    }
  }
}

extern "C" void kernel_launch(void* const* d_in, const int* in_sizes, int n_in,
                              void* d_out, int out_size, void* d_ws, size_t ws_size,
                              hipStream_t stream){
  const float* z      = (const float*)d_in[0];
  const float* anchor = (const float*)d_in[1];
  const float* projW  = (const float*)d_in[2];
  const float* projb  = (const float*)d_in[3];
  const float* eW1    = (const float*)d_in[4];
  const float* eb1    = (const float*)d_in[5];
  const float* eW2    = (const float*)d_in[6];
  const float* eb2    = (const float*)d_in[7];
  const float* nW1    = (const float*)d_in[8];
  const float* nb1    = (const float*)d_in[9];
  const float* nW2    = (const float*)d_in[10];
  const float* nb2    = (const float*)d_in[11];
  const float* cW1    = (const float*)d_in[12];
  const float* cb1    = (const float*)d_in[13];
  const float* cW2    = (const float*)d_in[14];
  float* out = (float*)d_out;

  char* w = (char*)d_ws;
  float* xA  = (float*)(w + O_XA);
  float* xB  = (float*)(w + O_XB);
  float* h   = (float*)(w + O_H);
  float* A   = (float*)(w + O_A);
  float* agg = (float*)(w + O_AGG);
  unsigned short* hbf   = (unsigned short*)(w + O_HBF);
  unsigned short* elist = (unsigned short*)(w + O_ELIST);
  int* counts = (int*)(w + O_CNT);
  int* Ucnt   = (int*)(w + O_UCNT);
  int* units  = (int*)(w + O_UNITS);
  int* done   = (int*)(w + O_DONE);
  unsigned* pk = (unsigned*)(w + O_PK);

  hipFuncSetAttribute((const void*)k_edge, hipFuncAttributeMaxDynamicSharedMemorySize, EDGE_SMEM);

  k_prep<<<313, 256, 0, stream>>>(eW1, eW2, cW1, pk, anchor, xA, xB, done);
  k_projAB<<<384, 128, 0, stream>>>(z, projW, projb, eW1, eb1, h, hbf, A, agg,
                                    xA, elist, counts, units, Ucnt, done + 0);
  // layer 0: read xA, accumulate into xB (seeded by k_prep)
  k_edge<<<G_EDGE, 512, EDGE_SMEM, stream>>>(xA, xB, A, hbf, elist, counts, units, Ucnt,
                                             agg, pk, eb2, cb1, cW2);
  k_nodeAB<<<384, 128, 0, stream>>>(nW1, nb1, nW2, nb2,
                                    eW1 + 272*128, eb1 + 128,
                                    h, hbf, agg, A, xB, xA,
                                    elist, counts, units, Ucnt, done + 1);
  // layer 1: read xB, accumulate into xA
  k_edge<<<G_EDGE, 512, EDGE_SMEM, stream>>>(xB, xA, A, hbf, elist, counts, units, Ucnt,
                                             agg, pk + PK_L, eb2 + 128, cb1 + 128, cW2 + 128);
  k_nodeAB<<<384, 128, 0, stream>>>(nW1 + 256*128, nb1 + 128, nW2 + 128*128, nb2 + 128,
                                    eW1 + 2*272*128, eb1 + 256,
                                    h, hbf, agg, A, xA, out,
                                    elist, counts, units, Ucnt, done + 2);
  // layer 2: read xA, accumulate into out
  k_edge<<<G_EDGE, 512, EDGE_SMEM, stream>>>(xA, out, A, hbf, elist, counts, units, Ucnt,
                                             agg, pk + 2*PK_L, eb2 + 256, cb1 + 256, cW2 + 256);
}

// Round 4
// 237.810 us; speedup vs baseline: 1.1942x; 1.1942x over previous
//
#include <hip/hip_runtime.h>
#include <hip/hip_bf16.h>

// Problem constants
#define NN 384
#define CUTOFF2 144.0f
#define GAMMA 1.7777778f   // (16/12)^2

// packed B-frag layout per layer (u32 units): [W1b 8192 | We 2048 | W2 8192 | C1 8192]
#define PK_L 26624
#define PK_WE 8192
#define PK_W2 10240
#define PK_C1 18432

#define G_EDGE 256
#define STG_F32 1152                    // 32 rows x 36 f32 per-wave stage
#define EDGE_SMEM ((PK_L + 8*STG_F32)*4)  // 143360 B

// ws byte offsets
#define O_XA 0
#define O_XB 4608
#define O_H 9216
#define O_A 205824
#define O_AGG 402432
#define O_HBF 599040
#define O_ELIST 697344
#define O_CNT 992256
#define O_UNITS 993856
#define O_DONE 1012288     // 3 Ucnt slots (zeroed by k_prep)
#define O_PK 1034816

typedef __bf16 bf16x8 __attribute__((ext_vector_type(8)));
typedef float f32x4 __attribute__((ext_vector_type(4)));

__device__ __forceinline__ unsigned short f2bf(float f){
  unsigned u = __float_as_uint(f);
  return (unsigned short)((u + 0x7fffu + ((u >> 16) & 1u)) >> 16);  // RNE
}
__device__ __forceinline__ unsigned pk2(float a, float b){
  return ((unsigned)f2bf(b) << 16) | f2bf(a);
}
__device__ __forceinline__ float silu(float x){ return x / (1.0f + __expf(-x)); }

// ---- pack weights into MFMA B-fragment order (bf16 pairs), 3 layers; block 312 = center+init
__global__ void k_prep(const float* __restrict__ eW1, const float* __restrict__ eW2,
                       const float* __restrict__ cW1, unsigned* __restrict__ pk,
                       const float* __restrict__ anchor, float* __restrict__ xA,
                       float* __restrict__ xB, int* __restrict__ ucnt){
  if (blockIdx.x == 312) {
    __shared__ float ssum[3];
    int t = threadIdx.x;
    if (t < 3) { ssum[t] = 0.f; ucnt[t] = 0; }
    __syncthreads();
    for (int n = t; n < 384; n += 256) {
      atomicAdd(&ssum[0], anchor[n*3]);
      atomicAdd(&ssum[1], anchor[n*3+1]);
      atomicAdd(&ssum[2], anchor[n*3+2]);
    }
    __syncthreads();
    float m0 = ssum[0]*(1.f/384.f), m1 = ssum[1]*(1.f/384.f), m2 = ssum[2]*(1.f/384.f);
    for (int n = t; n < 384; n += 256) {
      float v0 = anchor[n*3]-m0, v1 = anchor[n*3+1]-m1, v2 = anchor[n*3+2]-m2;
      xA[n*3]=v0; xA[n*3+1]=v1; xA[n*3+2]=v2;
      xB[n*3]=v0; xB[n*3+1]=v1; xB[n*3+2]=v2;
    }
    return;
  }
  int t = blockIdx.x * 256 + threadIdx.x;
  int layer = t / PK_L, r = t % PK_L;
  const float* src; int fr; int isWe = 0;
  if (r < PK_WE)        { fr = r;          src = eW1 + (layer*272 + 128)*128; }
  else if (r < PK_W2)   { fr = r - PK_WE;  src = eW1 + (layer*272 + 256)*128; isWe = 1; }
  else if (r < PK_C1)   { fr = r - PK_W2;  src = eW2 + layer*128*128; }
  else                  { fr = r - PK_C1;  src = cW1 + layer*128*128; }
  int tp = fr & 3, l = (fr >> 2) & 63, nc = fr >> 8;
  int n, k;
  if (!isWe) { n = nc >> 2; int c = nc & 3; k = c*32 + ((l>>4)<<3) + 2*tp; }
  else       { n = nc;                      k = ((l>>4)<<3) + 2*tp; }
  int nn = n*16 + (l & 15);
  float w0, w1;
  if (isWe) { w0 = (k < 16)   ? src[k*128+nn]     : 0.f;
              w1 = (k+1 < 16) ? src[(k+1)*128+nn] : 0.f; }
  else      { w0 = src[k*128+nn]; w1 = src[(k+1)*128+nn]; }
  pk[t] = ((unsigned)f2bf(w1) << 16) | f2bf(w0);
}

// ---- fence-free scan tail: compact edges, pad to x32, self-publish units
__device__ __forceinline__ void scan_units_tail(
    int i, int o, const float* __restrict__ x, unsigned short* __restrict__ elist,
    int* __restrict__ counts, int* __restrict__ units, int* __restrict__ ucntSlot,
    int* scnt, int* sbase){
  float xi0 = x[i*3], xi1 = x[i*3+1], xi2 = x[i*3+2];
  for (int j = o; j < 384; j += 128) {
    float d0 = xi0-x[j*3], d1 = xi1-x[j*3+1], d2 = xi2-x[j*3+2];
    float dd = d0*d0 + d1*d1 + d2*d2;
    bool msk = ((dd < CUTOFF2) && (j != i)) || (j == i-1) || (j == i+1);
    if (msk) { int ss = atomicAdd(scnt, 1); elist[i*384 + ss] = (unsigned short)j; }
  }
  __syncthreads();
  int cnt = *scnt;
  if (o < ((32 - (cnt & 31)) & 31)) elist[i*384 + cnt + o] = (unsigned short)i;
  int nu = (cnt + 31) >> 5;
  if (o == 0) { counts[i] = cnt; *sbase = atomicAdd(ucntSlot, nu); }
  __syncthreads();
  if (o < nu) units[*sbase + o] = i | (o << 16);   // plain store; consumed next kernel
}

// ---- h = z@projW + b; hbf; A = h@W1a + eb1; zero agg; + fused scan/units (layer 0)
__global__ void k_projAB(const float* __restrict__ z, const float* __restrict__ pW,
                         const float* __restrict__ pb, const float* __restrict__ eW1,
                         const float* __restrict__ eb1, float* __restrict__ h,
                         unsigned short* __restrict__ hbf, float* __restrict__ A,
                         float* __restrict__ agg, const float* __restrict__ x,
                         unsigned short* __restrict__ elist, int* __restrict__ counts,
                         int* __restrict__ units, int* __restrict__ ucntSlot){
  __shared__ float sz[64]; __shared__ float sh[128];
  __shared__ int scnt; __shared__ int sbase;
  int i = blockIdx.x, o = threadIdx.x;
  if (o == 0) scnt = 0;
  if (o < 64) sz[o] = z[i*64 + o];
  __syncthreads();
  float h0 = pb[o], h1 = 0.f, h2 = 0.f, h3 = 0.f;
  #pragma unroll 4
  for (int k = 0; k < 64; k += 4) {
    h0 += sz[k]   * pW[k*128 + o];
    h1 += sz[k+1] * pW[(k+1)*128 + o];
    h2 += sz[k+2] * pW[(k+2)*128 + o];
    h3 += sz[k+3] * pW[(k+3)*128 + o];
  }
  float hh = (h0 + h1) + (h2 + h3);
  h[i*128 + o] = hh; hbf[i*128 + o] = f2bf(hh); sh[o] = hh; agg[i*128 + o] = 0.f;
  __syncthreads();
  float a0 = eb1[o], a1 = 0.f, a2 = 0.f, a3 = 0.f;
  #pragma unroll 4
  for (int k = 0; k < 128; k += 4) {
    a0 += sh[k]   * eW1[k*128 + o];
    a1 += sh[k+1] * eW1[(k+1)*128 + o];
    a2 += sh[k+2] * eW1[(k+2)*128 + o];
    a3 += sh[k+3] * eW1[(k+3)*128 + o];
  }
  A[i*128 + o] = (a0 + a1) + (a2 + a3);
  scan_units_tail(i, o, x, elist, counts, units, ucntSlot, &scnt, &sbase);
}

// ---- node update, A/hbf for next layer, zero agg, seed xdst, + fused scan/units
__global__ void k_nodeAB(const float* __restrict__ nW1, const float* __restrict__ nb1,
                         const float* __restrict__ nW2, const float* __restrict__ nb2,
                         const float* __restrict__ eW1n, const float* __restrict__ eb1n,
                         float* __restrict__ h, unsigned short* __restrict__ hbf,
                         float* __restrict__ agg, float* __restrict__ A,
                         const float* __restrict__ xsrc, float* __restrict__ xdst,
                         unsigned short* __restrict__ elist, int* __restrict__ counts,
                         int* __restrict__ units, int* __restrict__ ucntSlot){
  __shared__ float sh[128], sg[128], st[128], shn[128];
  __shared__ int scnt; __shared__ int sbase;
  int i = blockIdx.x, o = threadIdx.x;
  if (o == 0) scnt = 0;
  sh[o] = h[i*128 + o]; sg[o] = agg[i*128 + o]; agg[i*128 + o] = 0.f;
  if (o < 3) xdst[i*3 + o] = xsrc[i*3 + o];
  __syncthreads();
  float a0 = nb1[o], a1 = 0.f, a2 = 0.f, a3 = 0.f;
  #pragma unroll 4
  for (int k = 0; k < 128; k += 4) {
    a0 += sh[k]   * nW1[k*128 + o];
    a1 += sh[k+1] * nW1[(k+1)*128 + o];
    a2 += sh[k+2] * nW1[(k+2)*128 + o];
    a3 += sh[k+3] * nW1[(k+3)*128 + o];
  }
  #pragma unroll 4
  for (int k = 0; k < 128; k += 4) {
    a0 += sg[k]   * nW1[(128+k)*128 + o];
    a1 += sg[k+1] * nW1[(129+k)*128 + o];
    a2 += sg[k+2] * nW1[(130+k)*128 + o];
    a3 += sg[k+3] * nW1[(131+k)*128 + o];
  }
  st[o] = silu((a0 + a1) + (a2 + a3));
  __syncthreads();
  float b0 = sh[o] + nb2[o], b1 = 0.f, b2 = 0.f, b3 = 0.f;
  #pragma unroll 4
  for (int k = 0; k < 128; k += 4) {
    b0 += st[k]   * nW2[k*128 + o];
    b1 += st[k+1] * nW2[(k+1)*128 + o];
    b2 += st[k+2] * nW2[(k+2)*128 + o];
    b3 += st[k+3] * nW2[(k+3)*128 + o];
  }
  float hn = (b0 + b1) + (b2 + b3);
  h[i*128 + o] = hn; hbf[i*128 + o] = f2bf(hn); shn[o] = hn;
  __syncthreads();
  float c0 = eb1n[o], c1 = 0.f, c2 = 0.f, c3 = 0.f;
  #pragma unroll 4
  for (int k = 0; k < 128; k += 4) {
    c0 += shn[k]   * eW1n[k*128 + o];
    c1 += shn[k+1] * eW1n[(k+1)*128 + o];
    c2 += shn[k+2] * eW1n[(k+2)*128 + o];
    c3 += shn[k+3] * eW1n[(k+3)*128 + o];
  }
  A[i*128 + o] = (c0 + c1) + (c2 + c3);
  scan_units_tail(i, o, xsrc, elist, counts, units, ucntSlot, &scnt, &sbase);
}

// ---- conflict-free C-layout -> A-frag transpose through per-wave f32 LDS pad
#define TRANSFORM(VA, VB, FA, FB)                                              \
  _Pragma("unroll")                                                            \
  for (int c = 0; c < 4; ++c) {                                                \
    _Pragma("unroll")                                                          \
    for (int tl = 0; tl < 2; ++tl) {                                           \
      int t = 2*c + tl;                                                        \
      _Pragma("unroll")                                                        \
      for (int r = 0; r < 4; ++r) {                                            \
        stg[(quad*4 + r)*36 + tl*16 + col0] = VA[t][r];                        \
        stg[(16 + quad*4 + r)*36 + tl*16 + col0] = VB[t][r];                   \
      }                                                                        \
    }                                                                          \
    __threadfence_block();                                                     \
    float4 lo = *(const float4*)(stg + col0*36 + quad*8);                      \
    float4 hi = *(const float4*)(stg + col0*36 + quad*8 + 4);                  \
    FA[c].u = make_uint4(pk2(lo.x,lo.y), pk2(lo.z,lo.w),                       \
                         pk2(hi.x,hi.y), pk2(hi.z,hi.w));                      \
    float4 lo2 = *(const float4*)(stg + (16 + col0)*36 + quad*8);              \
    float4 hi2 = *(const float4*)(stg + (16 + col0)*36 + quad*8 + 4);          \
    FB[c].u = make_uint4(pk2(lo2.x,lo2.y), pk2(lo2.z,lo2.w),                   \
                         pk2(hi2.x,hi2.y), pk2(hi2.z,hi2.w));                  \
    __threadfence_block();                                                     \
  }

// ---- MFMA edge kernel: wave = one unit (32 same-receiver edges, 2 A-frag sets)
__global__ __launch_bounds__(512, 1) void k_edge(
    const float* __restrict__ x_in, float* __restrict__ x_out,
    const float* __restrict__ Ag, const unsigned short* __restrict__ hbf,
    const unsigned short* __restrict__ elist, const int* __restrict__ counts,
    const int* __restrict__ units, const int* __restrict__ Ucnt,
    float* __restrict__ agg, const unsigned* __restrict__ pkl,
    const float* __restrict__ eb2g, const float* __restrict__ cb1g,
    const float* __restrict__ cw2g){
  extern __shared__ unsigned smem[];
  const int tid = threadIdx.x, q = tid & 63, s = tid >> 6;
  for (int idx = tid; idx < PK_L/4; idx += 512)
    ((uint4*)smem)[idx] = ((const uint4*)pkl)[idx];
  __syncthreads();

  const int col0 = q & 15, quad = q >> 4;
  float eb2v[8], cb1v[8], cw2v[8];
  #pragma unroll
  for (int t = 0; t < 8; ++t) {
    int c = t*16 + col0;
    eb2v[t] = eb2g[c]; cb1v[t] = cb1g[c]; cw2v[t] = cw2g[c];
  }
  float* stg = (float*)(smem + PK_L) + s*STG_F32;
  const int U = Ucnt[0];
  const f32x4 z4 = {0.f, 0.f, 0.f, 0.f};
  union U8 { uint4 u; bf16x8 v; };

  for (int u = blockIdx.x*8 + s; u < U; u += G_EDGE*8) {
    const int desc = units[u];
    const int i = desc & 0xffff, b = desc >> 16;
    int nvalid = counts[i] - b*32; if (nvalid > 32) nvalid = 32;
    const int j0 = (int)elist[i*384 + b*32 + col0];
    const int j1 = (int)elist[i*384 + b*32 + 16 + col0];

    const float xi0 = x_in[i*3], xi1 = x_in[i*3+1], xi2 = x_in[i*3+2];
    const float d0x = xi0 - x_in[j0*3], d0y = xi1 - x_in[j0*3+1], d0z = xi2 - x_in[j0*3+2];
    const float d1x = xi0 - x_in[j1*3], d1y = xi1 - x_in[j1*3+1], d1z = xi2 - x_in[j1*3+2];
    const float dd0 = sqrtf(d0x*d0x + d0y*d0y + d0z*d0z);
    const float dd1 = sqrtf(d1x*d1x + d1y*d1y + d1z*d1z);

    // RBF A-frags (K padded 16->32 with zeros; matching We frags are zero)
    U8 cve0, cve1;
    if (q < 32) {
      #pragma unroll
      for (int tp = 0; tp < 4; ++tp) {
        float k0 = (float)(quad*8 + 2*tp);
        float t00 = dd0 - 0.8f*k0, t01 = dd0 - 0.8f*(k0+1.f);
        float t10 = dd1 - 0.8f*k0, t11 = dd1 - 0.8f*(k0+1.f);
        (&cve0.u.x)[tp] = pk2(__expf(-GAMMA*t00*t00), __expf(-GAMMA*t01*t01));
        (&cve1.u.x)[tp] = pk2(__expf(-GAMMA*t10*t10), __expf(-GAMMA*t11*t11));
      }
    } else { cve0.u = make_uint4(0,0,0,0); cve1.u = make_uint4(0,0,0,0); }

    U8 ha0[4], ha1[4];
    #pragma unroll
    for (int c = 0; c < 4; ++c) {
      ha0[c].u = *(const uint4*)(hbf + j0*128 + c*32 + quad*8);
      ha1[c].u = *(const uint4*)(hbf + j1*128 + c*32 + quad*8);
    }
    float Aval[8];
    #pragma unroll
    for (int t = 0; t < 8; ++t) Aval[t] = Ag[i*128 + t*16 + col0];

    // GEMM1: m1 = silu(h_j@W1b + e@We + A_i), 32 rows
    f32x4 acc0[8], acc1[8];
    #pragma unroll
    for (int t = 0; t < 8; ++t) { acc0[t] = z4; acc1[t] = z4; }
    #pragma unroll
    for (int t = 0; t < 8; ++t) {
      #pragma unroll
      for (int c = 0; c < 4; ++c) {
        bf16x8 w = *(const bf16x8*)(smem + ((t*4 + c)*64 + q)*4);
        acc0[t] = __builtin_amdgcn_mfma_f32_16x16x32_bf16(ha0[c].v, w, acc0[t], 0, 0, 0);
        acc1[t] = __builtin_amdgcn_mfma_f32_16x16x32_bf16(ha1[c].v, w, acc1[t], 0, 0, 0);
      }
      bf16x8 we = *(const bf16x8*)(smem + PK_WE + (t*64 + q)*4);
      acc0[t] = __builtin_amdgcn_mfma_f32_16x16x32_bf16(cve0.v, we, acc0[t], 0, 0, 0);
      acc1[t] = __builtin_amdgcn_mfma_f32_16x16x32_bf16(cve1.v, we, acc1[t], 0, 0, 0);
    }
    #pragma unroll
    for (int t = 0; t < 8; ++t)
      #pragma unroll
      for (int r = 0; r < 4; ++r) {
        acc0[t][r] = silu(acc0[t][r] + Aval[t]);
        acc1[t][r] = silu(acc1[t][r] + Aval[t]);
      }

    U8 a20[4], a21[4];
    TRANSFORM(acc0, acc1, a20, a21);

    // GEMM2: m = silu(m1@eW2 + eb2)
    f32x4 m0[8], m1v[8];
    #pragma unroll
    for (int t = 0; t < 8; ++t) { m0[t] = z4; m1v[t] = z4; }
    #pragma unroll
    for (int t = 0; t < 8; ++t)
      #pragma unroll
      for (int c = 0; c < 4; ++c) {
        bf16x8 w = *(const bf16x8*)(smem + PK_W2 + ((t*4 + c)*64 + q)*4);
        m0[t] = __builtin_amdgcn_mfma_f32_16x16x32_bf16(a20[c].v, w, m0[t], 0, 0, 0);
        m1v[t] = __builtin_amdgcn_mfma_f32_16x16x32_bf16(a21[c].v, w, m1v[t], 0, 0, 0);
      }
    #pragma unroll
    for (int t = 0; t < 8; ++t) {
      float cs = 0.f;
      #pragma unroll
      for (int r = 0; r < 4; ++r) {
        m0[t][r] = silu(m0[t][r] + eb2v[t]);
        m1v[t][r] = silu(m1v[t][r] + eb2v[t]);
        if (quad*4 + r < nvalid) cs += m0[t][r];
        if (16 + quad*4 + r < nvalid) cs += m1v[t][r];
      }
      cs += __shfl_xor(cs, 16); cs += __shfl_xor(cs, 32);
      if (q < 16) atomicAdd(&agg[i*128 + t*16 + q], cs);
    }

    U8 a30[4], a31[4];
    TRANSFORM(m0, m1v, a30, a31);

    // GEMM3: c1 = silu(m@cW1 + cb1); w_row = c1 . cW2
    f32x4 c30[8], c31[8];
    #pragma unroll
    for (int t = 0; t < 8; ++t) { c30[t] = z4; c31[t] = z4; }
    #pragma unroll
    for (int t = 0; t < 8; ++t)
      #pragma unroll
      for (int c = 0; c < 4; ++c) {
        bf16x8 w = *(const bf16x8*)(smem + PK_C1 + ((t*4 + c)*64 + q)*4);
        c30[t] = __builtin_amdgcn_mfma_f32_16x16x32_bf16(a30[c].v, w, c30[t], 0, 0, 0);
        c31[t] = __builtin_amdgcn_mfma_f32_16x16x32_bf16(a31[c].v, w, c31[t], 0, 0, 0);
      }
    float p0[4], p1[4];
    #pragma unroll
    for (int r = 0; r < 4; ++r) {
      float pa = 0.f, pb = 0.f;
      #pragma unroll
      for (int t = 0; t < 8; ++t) {
        pa += silu(c30[t][r] + cb1v[t]) * cw2v[t];
        pb += silu(c31[t][r] + cb1v[t]) * cw2v[t];
      }
      if (quad*4 + r >= nvalid) pa = 0.f;
      if (16 + quad*4 + r >= nvalid) pb = 0.f;
      p0[r] = pa; p1[r] = pb;
    }
    #pragma unroll
    for (int r = 0; r < 4; ++r)
      #pragma unroll
      for (int off = 1; off < 16; off <<= 1) {
        p0[r] += __shfl_xor(p0[r], off);
        p1[r] += __shfl_xor(p1[r], off);
      }
    // dx_i contribution
    float dx0 = 0.f, dx1 = 0.f, dx2 = 0.f;
    #pragma unroll
    for (int r = 0; r < 4; ++r) {
      int el = quad*4 + r;
      float s0 = __shfl(d0x, el), s1 = __shfl(d0y, el), s2 = __shfl(d0z, el);
      if (col0 == 0) { dx0 += p0[r]*s0; dx1 += p0[r]*s1; dx2 += p0[r]*s2; }
      float u0 = __shfl(d1x, el), u1 = __shfl(d1y, el), u2 = __shfl(d1z, el);
      if (col0 == 0) { dx0 += p1[r]*u0; dx1 += p1[r]*u1; dx2 += p1[r]*u2; }
    }
    dx0 += __shfl_xor(dx0, 16); dx0 += __shfl_xor(dx0, 32);
    dx1 += __shfl_xor(dx1, 16); dx1 += __shfl_xor(dx1, 32);
    dx2 += __shfl_xor(dx2, 16); dx2 += __shfl_xor(dx2, 32);
    if (q == 0) {
      atomicAdd(&x_out[i*3 + 0], dx0);
      atomicAdd(&x_out[i*3 + 1], dx1);
      atomicAdd(&x_out[i*3 + 2], dx2);
    }
  }
}

extern "C" void kernel_launch(void* const* d_in, const int* in_sizes, int n_in,
                              void* d_out, int out_size, void* d_ws, size_t ws_size,
                              hipStream_t stream){
  const float* z      = (const float*)d_in[0];
  const float* anchor = (const float*)d_in[1];
  const float* projW  = (const float*)d_in[2];
  const float* projb  = (const float*)d_in[3];
  const float* eW1    = (const float*)d_in[4];
  const float* eb1    = (const float*)d_in[5];
  const float* eW2    = (const float*)d_in[6];
  const float* eb2    = (const float*)d_in[7];
  const float* nW1    = (const float*)d_in[8];
  const float* nb1    = (const float*)d_in[9];
  const float* nW2    = (const float*)d_in[10];
  const float* nb2    = (const float*)d_in[11];
  const float* cW1    = (const float*)d_in[12];
  const float* cb1    = (const float*)d_in[13];
  const float* cW2    = (const float*)d_in[14];
  float* out = (float*)d_out;

  char* w = (char*)d_ws;
  float* xA  = (float*)(w + O_XA);
  float* xB  = (float*)(w + O_XB);
  float* h   = (float*)(w + O_H);
  float* A   = (float*)(w + O_A);
  float* agg = (float*)(w + O_AGG);
  unsigned short* hbf   = (unsigned short*)(w + O_HBF);
  unsigned short* elist = (unsigned short*)(w + O_ELIST);
  int* counts = (int*)(w + O_CNT);
  int* units  = (int*)(w + O_UNITS);
  int* ucnt   = (int*)(w + O_DONE);   // 3 slots, zeroed by k_prep
  unsigned* pk = (unsigned*)(w + O_PK);

  hipFuncSetAttribute((const void*)k_edge, hipFuncAttributeMaxDynamicSharedMemorySize, EDGE_SMEM);

  k_prep<<<313, 256, 0, stream>>>(eW1, eW2, cW1, pk, anchor, xA, xB, ucnt);
  k_projAB<<<384, 128, 0, stream>>>(z, projW, projb, eW1, eb1, h, hbf, A, agg,
                                    xA, elist, counts, units, ucnt + 0);
  // layer 0: read xA, accumulate into xB (seeded by k_prep)
  k_edge<<<G_EDGE, 512, EDGE_SMEM, stream>>>(xA, xB, A, hbf, elist, counts, units, ucnt + 0,
                                             agg, pk, eb2, cb1, cW2);
  k_nodeAB<<<384, 128, 0, stream>>>(nW1, nb1, nW2, nb2,
                                    eW1 + 272*128, eb1 + 128,
                                    h, hbf, agg, A, xB, xA,
                                    elist, counts, units, ucnt + 1);
  // layer 1: read xB, accumulate into xA
  k_edge<<<G_EDGE, 512, EDGE_SMEM, stream>>>(xB, xA, A, hbf, elist, counts, units, ucnt + 1,
                                             agg, pk + PK_L, eb2 + 128, cb1 + 128, cW2 + 128);
  k_nodeAB<<<384, 128, 0, stream>>>(nW1 + 256*128, nb1 + 128, nW2 + 128*128, nb2 + 128,
                                    eW1 + 2*272*128, eb1 + 256,
                                    h, hbf, agg, A, xA, out,
                                    elist, counts, units, ucnt + 2);
  // layer 2: read xA, accumulate into out
  k_edge<<<G_EDGE, 512, EDGE_SMEM, stream>>>(xA, out, A, hbf, elist, counts, units, ucnt + 2,
                                             agg, pk + 2*PK_L, eb2 + 256, cb1 + 256, cW2 + 256);
}